// Round 4
// baseline (431.712 us; speedup 1.0000x reference)
//
#include <hip/hip_runtime.h>
#include <hip/hip_bf16.h>

typedef short bf16x8 __attribute__((ext_vector_type(8)));
typedef float f32x4 __attribute__((ext_vector_type(4)));

#define B_TOT 32768
#define ROWS  128           // 16 batches per WG

// ---- workspace layout (elements): bf16 W^T, written by prep_w each call ----
#define WSQ_ELT  0          // ushort [384][256]  qkv_w^T
#define WSP_ELT  98304      // ushort [256][128]  proj_w^T

// ---- main-kernel LDS layout (bytes) ----
#define WQ_OFF   0          // ushort[96][136]   26112
#define QK_OFF   26112      // ushort[128][104]  26624
#define BIAS_OFF 52736      // float[8][8][5]     1280
#define PB_OFF   54016      // float[256]         1024
#define OUT_OFF  0          // float[32][260]    33280 (epilogue overlay)
#define LDS_BYTES 55040

__device__ __forceinline__ unsigned short f2b(float f) {
    __hip_bfloat16 h = __float2bfloat16(f);   // RNE; compiler fuses pairs to v_cvt_pk_bf16_f32
    return reinterpret_cast<unsigned short&>(h);
}
__device__ __forceinline__ float b2f(unsigned short u) {
    union { unsigned u; float f; } v; v.u = ((unsigned)u) << 16; return v.f;
}

// ---------- pre-kernel: W (f32, row-major) -> W^T (bf16) in ws ----------
__global__ __launch_bounds__(256)
void prep_w(const float* __restrict__ qkv_w, const float* __restrict__ proj_w,
            unsigned short* __restrict__ ws)
{
    __shared__ float tile[64][65];
    const int bid = blockIdx.x;
    const float* src; unsigned short* dst; int ldw, ldk, tr0, tc0;
    if (bid < 24) {            // qkv: 4 k-tiles x 6 c-tiles
        int kr = bid / 6, cg = bid % 6;
        src = qkv_w; dst = ws + WSQ_ELT; ldw = 384; ldk = 256;
        tr0 = kr * 64; tc0 = cg * 64;
    } else {                   // proj: 2 k-tiles x 4 c-tiles
        int b = bid - 24; int kr = b / 4, cg = b % 4;
        src = proj_w; dst = ws + WSP_ELT; ldw = 256; ldk = 128;
        tr0 = kr * 64; tc0 = cg * 64;
    }
    const int t = threadIdx.x;
    #pragma unroll
    for (int i = 0; i < 16; ++i) {
        int idx = i * 256 + t;
        int r = idx >> 6, c = idx & 63;
        tile[r][c] = src[(size_t)(tr0 + r) * ldw + tc0 + c];
    }
    __syncthreads();
    #pragma unroll
    for (int i = 0; i < 2; ++i) {
        int idx = i * 256 + t;          // 0..511
        int c = idx >> 3, r0 = (idx & 7) * 8;
        union { unsigned short u[8]; uint4 v; } pk;
        #pragma unroll
        for (int j = 0; j < 8; ++j) pk.u[j] = f2b(tile[r0 + j][c]);
        *(uint4*)&dst[(size_t)(tc0 + c) * ldk + tr0 + r0] = pk.v;
    }
}

// ---------- main fused kernel ----------
__global__ __launch_bounds__(256)
void ta_fused(const float* __restrict__ x,
              const unsigned short* __restrict__ ws,
              const float* __restrict__ proj_b,
              const float* __restrict__ bias_table,
              const int* __restrict__ rel_index,
              float* __restrict__ out)
{
    __shared__ __align__(16) char smem[LDS_BYTES];
    unsigned short* wqs = (unsigned short*)(smem + WQ_OFF);
    unsigned short* qks = (unsigned short*)(smem + QK_OFF);
    float* bias_s = (float*)(smem + BIAS_OFF);
    float* pbs    = (float*)(smem + PB_OFF);
    float* outs   = (float*)(smem + OUT_OFF);

    const unsigned short* wsq = ws + WSQ_ELT;
    const unsigned short* wsp = ws + WSP_ELT;

    const int tid = threadIdx.x;
    const int l   = tid & 63;
    const int w   = tid >> 6;
    const int l15 = l & 15;
    const int l4  = l >> 4;
    const long wg = blockIdx.x;

    // ---- x A-fragments straight to registers: 2 m-tiles x 8 k-slices ----
    bf16x8 af[2][8];
    {
        const float* xg = x + wg * (size_t)(ROWS * 256);
        #pragma unroll
        for (int mt = 0; mt < 2; ++mt) {
            const float* xr = xg + (size_t)(32 * w + 16 * mt + l15) * 256;
            #pragma unroll
            for (int s = 0; s < 8; ++s) {
                f32x4 d0 = *(const f32x4*)(xr + s * 32 + l4 * 8);
                f32x4 d1 = *(const f32x4*)(xr + s * 32 + l4 * 8 + 4);
                union { unsigned short u[8]; bf16x8 v; } pk;
                #pragma unroll
                for (int j = 0; j < 4; ++j) pk.u[j] = f2b(d0[j]);
                #pragma unroll
                for (int j = 0; j < 4; ++j) pk.u[4 + j] = f2b(d1[j]);
                af[mt][s] = pk.v;
            }
        }
    }
    // ---- bias table + proj bias ----
    {
        int n = tid >> 5, m = (tid >> 2) & 7, hh = tid & 3;
        int ri = rel_index[n * 8 + m];
        bias_s[n * 40 + m * 5 + hh] = bias_table[ri * 4 + hh];
        pbs[tid] = proj_b[tid];
    }

    bf16x8 of[2][4];           // [m-tile][head] GEMM2 A-fragments
    const f32x4 zero4 = {0.f, 0.f, 0.f, 0.f};

    #pragma unroll 1
    for (int h = 0; h < 4; ++h) {
        f32x4 acc[6][2];
        #pragma unroll
        for (int i = 0; i < 6; ++i) { acc[i][0] = zero4; acc[i][1] = zero4; }

        #pragma unroll
        for (int c = 0; c < 2; ++c) {
            __syncthreads();      // wqs safe to overwrite
            #pragma unroll
            for (int u = 0; u < 6; ++u) {
                int idx = u * 256 + tid;          // 0..1535
                int rr = idx >> 4, seg = idx & 15;
                int p = rr >> 5, within = rr & 31;
                uint4 d = *(const uint4*)&wsq[(size_t)(p * 128 + h * 32 + within) * 256 + c * 128 + seg * 8];
                *(uint4*)&wqs[rr * 136 + seg * 8] = d;
            }
            __syncthreads();
            #pragma unroll
            for (int ks2 = 0; ks2 < 4; ++ks2) {
                #pragma unroll
                for (int ct = 0; ct < 6; ++ct) {
                    bf16x8 b = *(bf16x8*)&wqs[(ct * 16 + l15) * 136 + ks2 * 32 + l4 * 8];
                    acc[ct][0] = __builtin_amdgcn_mfma_f32_16x16x32_bf16(af[0][c * 4 + ks2], b, acc[ct][0], 0, 0, 0);
                    acc[ct][1] = __builtin_amdgcn_mfma_f32_16x16x32_bf16(af[1][c * 4 + ks2], b, acc[ct][1], 0, 0, 0);
                }
            }
        }
        // this head's q|k|v -> LDS rows owned by THIS wave only (no barrier needed)
        #pragma unroll
        for (int ct = 0; ct < 6; ++ct)
          #pragma unroll
          for (int mt = 0; mt < 2; ++mt)
            #pragma unroll
            for (int j = 0; j < 4; ++j) {
                int row = 32 * w + 16 * mt + l4 * 4 + j;
                qks[row * 104 + ct * 16 + l15] = f2b(acc[ct][mt][j]);
            }

        // ---- attention (head h), per m-tile; lane = (row l15, d-slice l4) ----
        #pragma unroll
        for (int mt = 0; mt < 2; ++mt) {
            const int r  = 32 * w + 16 * mt + l15;
            const int rb = r & ~7;
            const int n  = r & 7;
            float qf[8];
            {
                bf16x8 qv = *(bf16x8*)&qks[r * 104 + l4 * 8];
                #pragma unroll
                for (int j = 0; j < 8; ++j) qf[j] = b2f((unsigned short)qv[j]);
            }
            float sp[8];
            #pragma unroll
            for (int m = 0; m < 8; ++m) {
                bf16x8 kv = *(bf16x8*)&qks[(rb + m) * 104 + 32 + l4 * 8];
                float s = 0.f;
                #pragma unroll
                for (int j = 0; j < 8; ++j) s += qf[j] * b2f((unsigned short)kv[j]);
                sp[m] = s;
            }
            #pragma unroll
            for (int m = 0; m < 8; ++m) {
                sp[m] += __shfl_xor(sp[m], 16);
                sp[m] += __shfl_xor(sp[m], 32);
            }
            float mx = -1e30f;
            #pragma unroll
            for (int m = 0; m < 8; ++m) {
                sp[m] = sp[m] * 0.125f + bias_s[n * 40 + m * 5 + h];
                mx = fmaxf(mx, sp[m]);
            }
            float sum = 0.f;
            #pragma unroll
            for (int m = 0; m < 8; ++m) { sp[m] = __expf(sp[m] - mx); sum += sp[m]; }
            float inv = 1.f / sum;
            float o[8] = {0.f,0.f,0.f,0.f,0.f,0.f,0.f,0.f};
            #pragma unroll
            for (int m = 0; m < 8; ++m) {
                bf16x8 vv = *(bf16x8*)&qks[(rb + m) * 104 + 64 + l4 * 8];
                #pragma unroll
                for (int j = 0; j < 8; ++j) o[j] += sp[m] * b2f((unsigned short)vv[j]);
            }
            bf16x8 ofr;
            #pragma unroll
            for (int j = 0; j < 8; ++j) ofr[j] = (short)f2b(o[j] * inv);
            if      (h == 0) of[mt][0] = ofr;
            else if (h == 1) of[mt][1] = ofr;
            else if (h == 2) of[mt][2] = ofr;
            else             of[mt][3] = ofr;
        }
    }

    // ---- GEMM2: out = o @ proj_w + proj_b ----
    f32x4 acc2[4][4][2];   // [cc][ctl][mt]
    #pragma unroll
    for (int i = 0; i < 4; ++i)
      #pragma unroll
      for (int j = 0; j < 4; ++j) { acc2[i][j][0] = zero4; acc2[i][j][1] = zero4; }

    #pragma unroll
    for (int cc = 0; cc < 4; ++cc) {
        __syncthreads();         // wqs safe (also covers last attention reads at cc==0)
        #pragma unroll
        for (int u = 0; u < 4; ++u) {
            int idx = u * 256 + tid;          // 0..1023
            int rr = idx >> 4, seg = idx & 15;
            uint4 d = *(const uint4*)&wsp[(size_t)(cc * 64 + rr) * 128 + seg * 8];
            *(uint4*)&wqs[rr * 136 + seg * 8] = d;
        }
        __syncthreads();
        #pragma unroll
        for (int ctl = 0; ctl < 4; ++ctl) {
            #pragma unroll
            for (int ks = 0; ks < 4; ++ks) {
                bf16x8 b = *(bf16x8*)&wqs[(ctl * 16 + l15) * 136 + ks * 32 + l4 * 8];
                acc2[cc][ctl][0] = __builtin_amdgcn_mfma_f32_16x16x32_bf16(of[0][ks], b, acc2[cc][ctl][0], 0, 0, 0);
                acc2[cc][ctl][1] = __builtin_amdgcn_mfma_f32_16x16x32_bf16(of[1][ks], b, acc2[cc][ctl][1], 0, 0, 0);
            }
        }
    }

    // ---- epilogue: LDS-staged, fully coalesced f32 stores (4 passes of 32 rows) ----
    #pragma unroll
    for (int p = 0; p < 4; ++p) {
        __syncthreads();         // outs overlay safe / previous pass reads done
        if (w == p) {
            #pragma unroll
            for (int cc = 0; cc < 4; ++cc)
              #pragma unroll
              for (int ctl = 0; ctl < 4; ++ctl)
                #pragma unroll
                for (int mt = 0; mt < 2; ++mt)
                  #pragma unroll
                  for (int j = 0; j < 4; ++j) {
                      int row = 16 * mt + l4 * 4 + j;       // 0..31
                      int col = cc * 64 + ctl * 16 + l15;
                      outs[row * 260 + col] = acc2[cc][ctl][mt][j] + pbs[col];
                  }
        }
        __syncthreads();
        float* og = out + wg * (size_t)(ROWS * 256) + p * (32 * 256);
        #pragma unroll
        for (int i = 0; i < 4; ++i) {
            int f0 = (i * 256 + tid) * 8;     // 0..8191
            int row = f0 >> 8, col = f0 & 255;
            f32x4 v0 = *(f32x4*)&outs[row * 260 + col];
            f32x4 v1 = *(f32x4*)&outs[row * 260 + col + 4];
            *(f32x4*)(og + f0)     = v0;
            *(f32x4*)(og + f0 + 4) = v1;
        }
    }
}

extern "C" void kernel_launch(void* const* d_in, const int* in_sizes, int n_in,
                              void* d_out, int out_size, void* d_ws, size_t ws_size,
                              hipStream_t stream)
{
    (void)in_sizes; (void)n_in; (void)ws_size; (void)out_size;
    const float* x  = (const float*)d_in[0];
    const float* qw = (const float*)d_in[1];
    const float* pw = (const float*)d_in[2];
    const float* pb = (const float*)d_in[3];
    const float* bt = (const float*)d_in[4];
    const int*   ri = (const int*)d_in[5];
    float* o = (float*)d_out;
    unsigned short* ws = (unsigned short*)d_ws;

    hipLaunchKernelGGL(prep_w, dim3(32), dim3(256), 0, stream, qw, pw, ws);
    hipLaunchKernelGGL(ta_fused, dim3(B_TOT / 16), dim3(256), 0, stream,
                       x, ws, pb, bt, ri, o);
}

// Round 5
// 276.461 us; speedup vs baseline: 1.5616x; 1.5616x over previous
//
#include <hip/hip_runtime.h>
#include <hip/hip_bf16.h>

typedef short bf16x8 __attribute__((ext_vector_type(8)));
typedef float f32x4 __attribute__((ext_vector_type(4)));

#define B_TOT 32768
#define ROWS  128           // 16 batches per WG
#define NTHR  512           // 8 waves; wave w owns rows 16w..16w+15

// ---- workspace layout (elements): bf16 W^T, written by prep_w each call ----
#define WSQ_ELT  0          // ushort [384][256]  qkv_w^T
#define WSP_ELT  98304      // ushort [256][128]  proj_w^T

// ---- main-kernel LDS layout (bytes) ----
#define WQ_STR   136
#define QK_STR   104
#define WQ_OFF   0          // ushort[96][136]   26112
#define QK_OFF   26112      // ushort[128][104]  26624
#define BIAS_OFF 52736      // float[8][8][5]     1280
#define PB_OFF   54016      // float[256]         1024
#define OUT_OFF  0          // float[32][260]    33280 (epilogue overlay)
#define LDS_BYTES 55040     // -> 2 WG/CU (LDS), VGPR<=128 (launch_bounds) -> 16 waves/CU

static __device__ __forceinline__ unsigned short f2b(float f) {
    __hip_bfloat16 h = __float2bfloat16(f);   // RNE; pairs fuse to v_cvt_pk_bf16_f32
    return reinterpret_cast<unsigned short&>(h);
}
static __device__ __forceinline__ float b2f(unsigned short u) {
    union { unsigned u; float f; } v; v.u = ((unsigned)u) << 16; return v.f;
}

// ---------- pre-kernel: W (f32, row-major) -> W^T (bf16) in ws ----------
__global__ __launch_bounds__(256)
void prep_w(const float* __restrict__ qkv_w, const float* __restrict__ proj_w,
            unsigned short* __restrict__ ws)
{
    __shared__ float tile[64][65];
    const int bid = blockIdx.x;
    const float* src; unsigned short* dst; int ldw, ldk, tr0, tc0;
    if (bid < 24) {            // qkv: 4 k-tiles x 6 c-tiles
        int kr = bid / 6, cg = bid % 6;
        src = qkv_w; dst = ws + WSQ_ELT; ldw = 384; ldk = 256;
        tr0 = kr * 64; tc0 = cg * 64;
    } else {                   // proj: 2 k-tiles x 4 c-tiles
        int b = bid - 24; int kr = b / 4, cg = b % 4;
        src = proj_w; dst = ws + WSP_ELT; ldw = 256; ldk = 128;
        tr0 = kr * 64; tc0 = cg * 64;
    }
    const int t = threadIdx.x;
    #pragma unroll
    for (int i = 0; i < 16; ++i) {
        int idx = i * 256 + t;
        int r = idx >> 6, c = idx & 63;
        tile[r][c] = src[(size_t)(tr0 + r) * ldw + tc0 + c];
    }
    __syncthreads();
    #pragma unroll
    for (int i = 0; i < 2; ++i) {
        int idx = i * 256 + t;          // 0..511
        int c = idx >> 3, r0 = (idx & 7) * 8;
        union { unsigned short u[8]; uint4 v; } pk;
        #pragma unroll
        for (int j = 0; j < 8; ++j) pk.u[j] = f2b(tile[r0 + j][c]);
        *(uint4*)&dst[(size_t)(tc0 + c) * ldk + tr0 + r0] = pk.v;
    }
}

// ---------- main fused kernel ----------
__global__ __launch_bounds__(NTHR, 4)    // cap VGPR at 128 -> 2 WG/CU
void ta_fused(const float* __restrict__ x,
              const unsigned short* __restrict__ ws,
              const float* __restrict__ proj_b,
              const float* __restrict__ bias_table,
              const int* __restrict__ rel_index,
              float* __restrict__ out)
{
    __shared__ __align__(16) char smem[LDS_BYTES];
    unsigned short* wqs = (unsigned short*)(smem + WQ_OFF);
    unsigned short* qks = (unsigned short*)(smem + QK_OFF);
    float* bias_s = (float*)(smem + BIAS_OFF);
    float* pbs    = (float*)(smem + PB_OFF);
    float* outs   = (float*)(smem + OUT_OFF);

    const unsigned short* wsq = ws + WSQ_ELT;
    const unsigned short* wsp = ws + WSP_ELT;

    const int tid = threadIdx.x;
    const int l   = tid & 63;
    const int w   = tid >> 6;          // 0..7
    const int l15 = l & 15;
    const int l4  = l >> 4;
    const long wg = blockIdx.x;

    // ---- x A-fragments straight to registers (16 rows per wave) ----
    bf16x8 af[8];
    {
        const float* xr = x + wg * (size_t)(ROWS * 256) + (size_t)(16 * w + l15) * 256;
        #pragma unroll
        for (int s = 0; s < 8; ++s) {
            f32x4 d0 = *(const f32x4*)(xr + s * 32 + l4 * 8);
            f32x4 d1 = *(const f32x4*)(xr + s * 32 + l4 * 8 + 4);
            union { unsigned short u[8]; bf16x8 v; } pk;
            #pragma unroll
            for (int j = 0; j < 4; ++j) pk.u[j] = f2b(d0[j]);
            #pragma unroll
            for (int j = 0; j < 4; ++j) pk.u[4 + j] = f2b(d1[j]);
            af[s] = pk.v;
        }
    }
    // ---- bias table + proj bias ----
    if (tid < 256) {
        int n = tid >> 5, m = (tid >> 2) & 7, hh = tid & 3;
        int ri = rel_index[n * 8 + m];
        bias_s[n * 40 + m * 5 + hh] = bias_table[ri * 4 + hh];
        pbs[tid] = proj_b[tid];
    }

    // ---- prefetch stage (h=0, c=0) ----
    uint4 pfq[3];
    uint4 pfp[2];
    #pragma unroll
    for (int u = 0; u < 3; ++u) {
        int idx = u * NTHR + tid;          // 0..1535
        int rr = idx >> 4, seg = idx & 15;
        int p = rr >> 5, wi = rr & 31;
        pfq[u] = *(const uint4*)&wsq[(size_t)(p * 128 + wi) * 256 + seg * 8];
    }

    bf16x8 of0, of1, of2, of3;
    const f32x4 zero4 = {0.f, 0.f, 0.f, 0.f};

    #pragma unroll 1
    for (int h = 0; h < 4; ++h) {
        f32x4 acc[6];
        #pragma unroll
        for (int i = 0; i < 6; ++i) acc[i] = zero4;

        #pragma unroll
        for (int c = 0; c < 2; ++c) {
            __syncthreads();            // previous stage's wqs readers done
            // write prefetched W slice
            #pragma unroll
            for (int u = 0; u < 3; ++u) {
                int idx = u * NTHR + tid;
                int rr = idx >> 4, seg = idx & 15;
                *(uint4*)&wqs[rr * WQ_STR + seg * 8] = pfq[u];
            }
            // issue next stage's global loads (hidden under this stage's MFMA)
            if (c == 0) {
                #pragma unroll
                for (int u = 0; u < 3; ++u) {
                    int idx = u * NTHR + tid;
                    int rr = idx >> 4, seg = idx & 15;
                    int p = rr >> 5, wi = rr & 31;
                    pfq[u] = *(const uint4*)&wsq[(size_t)(p * 128 + h * 32 + wi) * 256 + 128 + seg * 8];
                }
            } else if (h < 3) {
                #pragma unroll
                for (int u = 0; u < 3; ++u) {
                    int idx = u * NTHR + tid;
                    int rr = idx >> 4, seg = idx & 15;
                    int p = rr >> 5, wi = rr & 31;
                    pfq[u] = *(const uint4*)&wsq[(size_t)(p * 128 + (h + 1) * 32 + wi) * 256 + seg * 8];
                }
            } else {
                #pragma unroll
                for (int u = 0; u < 2; ++u) {
                    int idx = u * NTHR + tid;
                    int rr = idx >> 4, seg = idx & 15;
                    pfp[u] = *(const uint4*)&wsp[(size_t)rr * 128 + seg * 8];
                }
            }
            __syncthreads();            // wqs writes visible
            #pragma unroll
            for (int ks2 = 0; ks2 < 4; ++ks2) {
                bf16x8 a = af[c * 4 + ks2];
                #pragma unroll
                for (int ct = 0; ct < 6; ++ct) {
                    bf16x8 b = *(bf16x8*)&wqs[(ct * 16 + l15) * WQ_STR + ks2 * 32 + l4 * 8];
                    acc[ct] = __builtin_amdgcn_mfma_f32_16x16x32_bf16(a, b, acc[ct], 0, 0, 0);
                }
            }
        }
        // this head's q|k|v -> wave-private qks rows (in-order DS per wave: no barrier)
        #pragma unroll
        for (int ct = 0; ct < 6; ++ct)
          #pragma unroll
          for (int j = 0; j < 4; ++j) {
              int row = 16 * w + l4 * 4 + j;
              qks[row * QK_STR + ct * 16 + l15] = f2b(acc[ct][j]);
          }

        // ---- attention (head h): lane = (row l15 of wave tile, d-slice l4) ----
        {
            const int r  = 16 * w + l15;
            const int rb = r & ~7;
            const int n  = r & 7;
            float qf[8];
            {
                bf16x8 qv = *(bf16x8*)&qks[r * QK_STR + l4 * 8];
                #pragma unroll
                for (int j = 0; j < 8; ++j) qf[j] = b2f((unsigned short)qv[j]);
            }
            float sp[8];
            #pragma unroll
            for (int m = 0; m < 8; ++m) {
                bf16x8 kv = *(bf16x8*)&qks[(rb + m) * QK_STR + 32 + l4 * 8];
                float s = 0.f;
                #pragma unroll
                for (int j = 0; j < 8; ++j) s += qf[j] * b2f((unsigned short)kv[j]);
                sp[m] = s;
            }
            #pragma unroll
            for (int m = 0; m < 8; ++m) {
                sp[m] += __shfl_xor(sp[m], 16);
                sp[m] += __shfl_xor(sp[m], 32);
            }
            float mx = -1e30f;
            #pragma unroll
            for (int m = 0; m < 8; ++m) {
                sp[m] = sp[m] * 0.125f + bias_s[n * 40 + m * 5 + h];
                mx = fmaxf(mx, sp[m]);
            }
            float sum = 0.f;
            #pragma unroll
            for (int m = 0; m < 8; ++m) { sp[m] = __expf(sp[m] - mx); sum += sp[m]; }
            float inv = 1.f / sum;
            float o[8] = {0.f,0.f,0.f,0.f,0.f,0.f,0.f,0.f};
            #pragma unroll
            for (int m = 0; m < 8; ++m) {
                bf16x8 vv = *(bf16x8*)&qks[(rb + m) * QK_STR + 64 + l4 * 8];
                #pragma unroll
                for (int j = 0; j < 8; ++j) o[j] += sp[m] * b2f((unsigned short)vv[j]);
            }
            bf16x8 ofr;
            #pragma unroll
            for (int j = 0; j < 8; ++j) ofr[j] = (short)f2b(o[j] * inv);
            if      (h == 0) of0 = ofr;
            else if (h == 1) of1 = ofr;
            else if (h == 2) of2 = ofr;
            else             of3 = ofr;
        }
    }

    // ---- GEMM2: out = o @ proj_w + proj_b ----
    f32x4 acc2[4][4];
    #pragma unroll
    for (int i = 0; i < 4; ++i)
      #pragma unroll
      for (int j = 0; j < 4; ++j) acc2[i][j] = zero4;

    #pragma unroll
    for (int cc = 0; cc < 4; ++cc) {
        __syncthreads();                // previous wqs readers done
        #pragma unroll
        for (int u = 0; u < 2; ++u) {
            int idx = u * NTHR + tid;   // 0..1023
            int rr = idx >> 4, seg = idx & 15;
            *(uint4*)&wqs[rr * WQ_STR + seg * 8] = pfp[u];
        }
        if (cc < 3) {
            #pragma unroll
            for (int u = 0; u < 2; ++u) {
                int idx = u * NTHR + tid;
                int rr = idx >> 4, seg = idx & 15;
                pfp[u] = *(const uint4*)&wsp[(size_t)((cc + 1) * 64 + rr) * 128 + seg * 8];
            }
        }
        __syncthreads();
        #pragma unroll
        for (int ctl = 0; ctl < 4; ++ctl) {
            #pragma unroll
            for (int ks = 0; ks < 4; ++ks) {
                bf16x8 b = *(bf16x8*)&wqs[(ctl * 16 + l15) * WQ_STR + ks * 32 + l4 * 8];
                bf16x8 a = (ks == 0) ? of0 : (ks == 1) ? of1 : (ks == 2) ? of2 : of3;
                acc2[cc][ctl] = __builtin_amdgcn_mfma_f32_16x16x32_bf16(a, b, acc2[cc][ctl], 0, 0, 0);
            }
        }
    }

    // ---- epilogue: LDS-staged, fully coalesced f32 stores (4 passes of 32 rows) ----
    #pragma unroll
    for (int p = 0; p < 4; ++p) {
        __syncthreads();                // outs overlay safe / previous pass reads done
        if ((w >> 1) == p) {
            #pragma unroll
            for (int cc = 0; cc < 4; ++cc)
              #pragma unroll
              for (int ctl = 0; ctl < 4; ++ctl)
                #pragma unroll
                for (int j = 0; j < 4; ++j) {
                    int row = 16 * (w & 1) + l4 * 4 + j;     // 0..31
                    int col = cc * 64 + ctl * 16 + l15;
                    outs[row * 260 + col] = acc2[cc][ctl][j] + pbs[col];
                }
        }
        __syncthreads();
        float* og = out + wg * (size_t)(ROWS * 256) + p * (32 * 256);
        #pragma unroll
        for (int i = 0; i < 2; ++i) {
            int f0 = (i * NTHR + tid) * 8;    // 0..8191
            int row = f0 >> 8, col = f0 & 255;
            f32x4 v0 = *(f32x4*)&outs[row * 260 + col];
            f32x4 v1 = *(f32x4*)&outs[row * 260 + col + 4];
            *(f32x4*)(og + f0)     = v0;
            *(f32x4*)(og + f0 + 4) = v1;
        }
    }
}

extern "C" void kernel_launch(void* const* d_in, const int* in_sizes, int n_in,
                              void* d_out, int out_size, void* d_ws, size_t ws_size,
                              hipStream_t stream)
{
    (void)in_sizes; (void)n_in; (void)ws_size; (void)out_size;
    const float* x  = (const float*)d_in[0];
    const float* qw = (const float*)d_in[1];
    const float* pw = (const float*)d_in[2];
    const float* pb = (const float*)d_in[3];
    const float* bt = (const float*)d_in[4];
    const int*   ri = (const int*)d_in[5];
    float* o = (float*)d_out;
    unsigned short* ws = (unsigned short*)d_ws;

    hipLaunchKernelGGL(prep_w, dim3(32), dim3(256), 0, stream, qw, pw, ws);
    hipLaunchKernelGGL(ta_fused, dim3(B_TOT / 16), dim3(NTHR), 0, stream,
                       x, ws, pb, bt, ri, o);
}

// Round 6
// 225.335 us; speedup vs baseline: 1.9159x; 1.2269x over previous
//
#include <hip/hip_runtime.h>
#include <hip/hip_bf16.h>

typedef short bf16x8 __attribute__((ext_vector_type(8)));
typedef float f32x4 __attribute__((ext_vector_type(4)));

#define B_TOT 32768
#define ROWS  128           // 16 batches per WG
#define NTHR  512           // 8 waves; wave w owns rows 16w..16w+15

// ---- workspace layout (elements): bf16 W^T, written by prep_w each call ----
#define WSQ_ELT  0          // ushort [384][256]  qkv_w^T
#define WSP_ELT  98304      // ushort [256][128]  proj_w^T

// ---- main-kernel LDS layout (bytes) ----
#define WQ_STR   136
#define QK_STR   104
#define CH_STR   68         // f32 stride of epilogue chunk (272B, 16B-aligned)
#define WQ_OFF   0          // ushort[96][136]            26112
#define QK_OFF   26112      // ushort[128][104] / chunk float[128][68]  34816
#define BIAS_OFF 60928      // float[8][8][5]              1280
#define PB_OFF   62208      // float[256]                  1024
#define LDS_BYTES 63232     // 2 WG/CU; VGPR<=128 via launch_bounds -> 16 waves/CU

static __device__ __forceinline__ unsigned short f2b(float f) {
    __hip_bfloat16 h = __float2bfloat16(f);   // RNE; pairs fuse to v_cvt_pk_bf16_f32
    return reinterpret_cast<unsigned short&>(h);
}
static __device__ __forceinline__ float b2f(unsigned short u) {
    union { unsigned u; float f; } v; v.u = ((unsigned)u) << 16; return v.f;
}

// ---------- pre-kernel: W (f32, row-major) -> W^T (bf16) in ws ----------
__global__ __launch_bounds__(256)
void prep_w(const float* __restrict__ qkv_w, const float* __restrict__ proj_w,
            unsigned short* __restrict__ ws)
{
    __shared__ float tile[64][65];
    const int bid = blockIdx.x;
    const float* src; unsigned short* dst; int ldw, ldk, tr0, tc0;
    if (bid < 24) {            // qkv: 4 k-tiles x 6 c-tiles
        int kr = bid / 6, cg = bid % 6;
        src = qkv_w; dst = ws + WSQ_ELT; ldw = 384; ldk = 256;
        tr0 = kr * 64; tc0 = cg * 64;
    } else {                   // proj: 2 k-tiles x 4 c-tiles
        int b = bid - 24; int kr = b / 4, cg = b % 4;
        src = proj_w; dst = ws + WSP_ELT; ldw = 256; ldk = 128;
        tr0 = kr * 64; tc0 = cg * 64;
    }
    const int t = threadIdx.x;
    #pragma unroll
    for (int i = 0; i < 16; ++i) {
        int idx = i * 256 + t;
        int r = idx >> 6, c = idx & 63;
        tile[r][c] = src[(size_t)(tr0 + r) * ldw + tc0 + c];
    }
    __syncthreads();
    #pragma unroll
    for (int i = 0; i < 2; ++i) {
        int idx = i * 256 + t;          // 0..511
        int c = idx >> 3, r0 = (idx & 7) * 8;
        union { unsigned short u[8]; uint4 v; } pk;
        #pragma unroll
        for (int j = 0; j < 8; ++j) pk.u[j] = f2b(tile[r0 + j][c]);
        *(uint4*)&dst[(size_t)(tc0 + c) * ldk + tr0 + r0] = pk.v;
    }
}

// ---------- main fused kernel ----------
__global__ __launch_bounds__(NTHR, 4)    // 128 unified regs/wave -> 2 WG/CU, no spill by design
void ta_fused(const float* __restrict__ x,
              const unsigned short* __restrict__ ws,
              const float* __restrict__ proj_b,
              const float* __restrict__ bias_table,
              const int* __restrict__ rel_index,
              float* __restrict__ out)
{
    __shared__ __align__(16) char smem[LDS_BYTES];
    unsigned short* wqs = (unsigned short*)(smem + WQ_OFF);
    unsigned short* qks = (unsigned short*)(smem + QK_OFF);
    float* chunk  = (float*)(smem + QK_OFF);      // overlays qks (dead in GEMM2)
    float* bias_s = (float*)(smem + BIAS_OFF);
    float* pbs    = (float*)(smem + PB_OFF);

    const unsigned short* wsq = ws + WSQ_ELT;
    const unsigned short* wsp = ws + WSP_ELT;

    const int tid = threadIdx.x;
    const int l   = tid & 63;
    const int w   = tid >> 6;          // 0..7
    const int l15 = l & 15;
    const int l4  = l >> 4;
    const long wg = blockIdx.x;

    // ---- x A-fragments straight to registers (16 rows per wave) ----
    bf16x8 af[8];
    {
        const float* xr = x + wg * (size_t)(ROWS * 256) + (size_t)(16 * w + l15) * 256;
        #pragma unroll
        for (int s = 0; s < 8; ++s) {
            f32x4 d0 = *(const f32x4*)(xr + s * 32 + l4 * 8);
            f32x4 d1 = *(const f32x4*)(xr + s * 32 + l4 * 8 + 4);
            union { unsigned short u[8]; bf16x8 v; } pk;
            #pragma unroll
            for (int j = 0; j < 4; ++j) pk.u[j] = f2b(d0[j]);
            #pragma unroll
            for (int j = 0; j < 4; ++j) pk.u[4 + j] = f2b(d1[j]);
            af[s] = pk.v;
        }
    }
    // ---- bias table + proj bias ----
    if (tid < 256) {
        int n = tid >> 5, m = (tid >> 2) & 7, hh = tid & 3;
        int ri = rel_index[n * 8 + m];
        bias_s[n * 40 + m * 5 + hh] = bias_table[ri * 4 + hh];
        pbs[tid] = proj_b[tid];
    }

    bf16x8 of0, of1, of2, of3;
    const f32x4 zero4 = {0.f, 0.f, 0.f, 0.f};

    #pragma unroll 1
    for (int h = 0; h < 4; ++h) {
        f32x4 acc[6];
        #pragma unroll
        for (int i = 0; i < 6; ++i) acc[i] = zero4;

        #pragma unroll
        for (int c = 0; c < 2; ++c) {
            __syncthreads();            // previous stage's wqs readers done
            // stage qkv_w^T slice: 96 rows x 128 k (L2-hot after first round)
            #pragma unroll
            for (int u = 0; u < 3; ++u) {
                int idx = u * NTHR + tid;          // 0..1535
                int rr = idx >> 4, seg = idx & 15;
                int p = rr >> 5, wi = rr & 31;
                uint4 d = *(const uint4*)&wsq[(size_t)(p * 128 + h * 32 + wi) * 256 + c * 128 + seg * 8];
                *(uint4*)&wqs[rr * WQ_STR + seg * 8] = d;
            }
            __syncthreads();            // wqs writes visible
            #pragma unroll
            for (int ks2 = 0; ks2 < 4; ++ks2) {
                bf16x8 a = af[c * 4 + ks2];
                #pragma unroll
                for (int ct = 0; ct < 6; ++ct) {
                    bf16x8 b = *(bf16x8*)&wqs[(ct * 16 + l15) * WQ_STR + ks2 * 32 + l4 * 8];
                    acc[ct] = __builtin_amdgcn_mfma_f32_16x16x32_bf16(a, b, acc[ct], 0, 0, 0);
                }
            }
        }
        // this head's q|k|v -> wave-private qks rows (in-order DS per wave: no barrier)
        #pragma unroll
        for (int ct = 0; ct < 6; ++ct)
          #pragma unroll
          for (int j = 0; j < 4; ++j) {
              int row = 16 * w + l4 * 4 + j;
              qks[row * QK_STR + ct * 16 + l15] = f2b(acc[ct][j]);
          }

        // ---- attention (head h): lane = (row l15 of wave tile, d-slice l4) ----
        {
            const int r  = 16 * w + l15;
            const int rb = r & ~7;
            const int n  = r & 7;
            float qf[8];
            {
                bf16x8 qv = *(bf16x8*)&qks[r * QK_STR + l4 * 8];
                #pragma unroll
                for (int j = 0; j < 8; ++j) qf[j] = b2f((unsigned short)qv[j]);
            }
            float sp[8];
            #pragma unroll
            for (int m = 0; m < 8; ++m) {
                bf16x8 kv = *(bf16x8*)&qks[(rb + m) * QK_STR + 32 + l4 * 8];
                float s = 0.f;
                #pragma unroll
                for (int j = 0; j < 8; ++j) s += qf[j] * b2f((unsigned short)kv[j]);
                sp[m] = s;
            }
            #pragma unroll
            for (int m = 0; m < 8; ++m) {
                sp[m] += __shfl_xor(sp[m], 16);
                sp[m] += __shfl_xor(sp[m], 32);
            }
            float mx = -1e30f;
            #pragma unroll
            for (int m = 0; m < 8; ++m) {
                sp[m] = sp[m] * 0.125f + bias_s[n * 40 + m * 5 + h];
                mx = fmaxf(mx, sp[m]);
            }
            float sum = 0.f;
            #pragma unroll
            for (int m = 0; m < 8; ++m) { sp[m] = __expf(sp[m] - mx); sum += sp[m]; }
            float inv = 1.f / sum;
            float o[8] = {0.f,0.f,0.f,0.f,0.f,0.f,0.f,0.f};
            #pragma unroll
            for (int m = 0; m < 8; ++m) {
                bf16x8 vv = *(bf16x8*)&qks[(rb + m) * QK_STR + 64 + l4 * 8];
                #pragma unroll
                for (int j = 0; j < 8; ++j) o[j] += sp[m] * b2f((unsigned short)vv[j]);
            }
            bf16x8 ofr;
            #pragma unroll
            for (int j = 0; j < 8; ++j) ofr[j] = (short)f2b(o[j] * inv);
            if      (h == 0) of0 = ofr;
            else if (h == 1) of1 = ofr;
            else if (h == 2) of2 = ofr;
            else             of3 = ofr;
        }
    }

    // ---- GEMM2 + fused epilogue, one 64-col block at a time (acc2 = 16 regs) ----
    #pragma unroll 1
    for (int cc = 0; cc < 4; ++cc) {
        __syncthreads();                // prev MFMA B-reads + prev chunk copy-reads done
        #pragma unroll
        for (int u = 0; u < 2; ++u) {
            int idx = u * NTHR + tid;   // 0..1023
            int rr = idx >> 4, seg = idx & 15;
            uint4 d = *(const uint4*)&wsp[(size_t)(cc * 64 + rr) * 128 + seg * 8];
            *(uint4*)&wqs[rr * WQ_STR + seg * 8] = d;
        }
        __syncthreads();                // wqs ready

        f32x4 acc2[4];
        #pragma unroll
        for (int i = 0; i < 4; ++i) acc2[i] = zero4;
        #pragma unroll
        for (int ctl = 0; ctl < 4; ++ctl) {
            #pragma unroll
            for (int ks = 0; ks < 4; ++ks) {
                bf16x8 b = *(bf16x8*)&wqs[(ctl * 16 + l15) * WQ_STR + ks * 32 + l4 * 8];
                bf16x8 a = (ks == 0) ? of0 : (ks == 1) ? of1 : (ks == 2) ? of2 : of3;
                acc2[ctl] = __builtin_amdgcn_mfma_f32_16x16x32_bf16(a, b, acc2[ctl], 0, 0, 0);
            }
        }
        // epilogue-write this 64-col block into chunk (wave-private rows)
        #pragma unroll
        for (int ctl = 0; ctl < 4; ++ctl)
          #pragma unroll
          for (int j = 0; j < 4; ++j) {
              int row = 16 * w + l4 * 4 + j;
              int col = ctl * 16 + l15;
              chunk[row * CH_STR + col] = acc2[ctl][j] + pbs[cc * 64 + col];
          }
        __syncthreads();                // chunk complete
        // copy chunk -> global, fully coalesced (full 128B lines)
        {
            float* og = out + wg * (size_t)(ROWS * 256) + cc * 64;
            #pragma unroll
            for (int i = 0; i < 4; ++i) {
                int f0 = i * NTHR + tid;          // 0..2047 f32x4-chunks
                int row = f0 >> 4, c4 = f0 & 15;
                f32x4 v = *(f32x4*)&chunk[row * CH_STR + c4 * 4];
                *(f32x4*)(og + (size_t)row * 256 + c4 * 4) = v;
            }
        }
    }
}

extern "C" void kernel_launch(void* const* d_in, const int* in_sizes, int n_in,
                              void* d_out, int out_size, void* d_ws, size_t ws_size,
                              hipStream_t stream)
{
    (void)in_sizes; (void)n_in; (void)ws_size; (void)out_size;
    const float* x  = (const float*)d_in[0];
    const float* qw = (const float*)d_in[1];
    const float* pw = (const float*)d_in[2];
    const float* pb = (const float*)d_in[3];
    const float* bt = (const float*)d_in[4];
    const int*   ri = (const int*)d_in[5];
    float* o = (float*)d_out;
    unsigned short* ws = (unsigned short*)d_ws;

    hipLaunchKernelGGL(prep_w, dim3(32), dim3(256), 0, stream, qw, pw, ws);
    hipLaunchKernelGGL(ta_fused, dim3(B_TOT / 16), dim3(NTHR), 0, stream,
                       x, ws, pb, bt, ri, o);
}